// Round 1
// baseline (496.213 us; speedup 1.0000x reference)
//
#include <hip/hip_runtime.h>
#include <hip/hip_bf16.h>
#include <cstdint>
#include <cstddef>
#include <cmath>

typedef __attribute__((ext_vector_type(8))) short short8;
typedef __attribute__((ext_vector_type(4))) float f32x4;

static constexpr int BB = 2, T = 2048, C = 2048, H = 16, HD = 128;
static constexpr int M = BB * T;              // 4096
static constexpr size_t BTC = (size_t)BB * T * C;      // 8388608 (= B*H*T*HD)

__device__ __forceinline__ short f2bf(float f) {
    union { float f; uint32_t u; } v; v.f = f;
    uint32_t u = v.u;
    uint32_t r = (u + 0x7fffu + ((u >> 16) & 1u)) >> 16;
    return (short)r;
}

__device__ __forceinline__ void gl_lds16(const void* g, void* l) {
    __builtin_amdgcn_global_load_lds(
        (const __attribute__((address_space(1))) unsigned int*)g,
        (__attribute__((address_space(3))) unsigned int*)l, 16, 0, 0);
}

// ---------- f32 -> bf16 bulk convert (vectorized, G13) ----------
__global__ void cvt_bf16(const float* __restrict__ in, short* __restrict__ out, int n) {
    int i = (blockIdx.x * 256 + threadIdx.x) * 8;
    if (i >= n) return;
    float4 a = *(const float4*)(in + i);
    float4 b = *(const float4*)(in + i + 4);
    short8 o;
    o[0] = f2bf(a.x); o[1] = f2bf(a.y); o[2] = f2bf(a.z); o[3] = f2bf(a.w);
    o[4] = f2bf(b.x); o[5] = f2bf(b.y); o[6] = f2bf(b.z); o[7] = f2bf(b.w);
    *(short8*)(out + i) = o;
}

// ---------- 128x128 bf16 GEMM, C = A @ B^T + bias (m97 structure) ----------
// A [Mrows][K] row-major bf16, Bw [Ncols][K] row-major bf16.
// EPI 0: QKV epilogue (scatter q/k/v). EPI 1: plain f32 store.
template<int EPI>
__global__ void gemm_bt(const short* __restrict__ A, const short* __restrict__ Bw,
                        const float* __restrict__ bias,
                        float* __restrict__ outF,
                        short* __restrict__ q_ws, short* __restrict__ k_ws,
                        int Mdim, int Ndim, int K) {
    __shared__ __attribute__((aligned(16))) short As[128 * 32];
    __shared__ __attribute__((aligned(16))) short Bs[128 * 32];
    int t = threadIdx.x;
    int w = t >> 6, l = t & 63;
    int lr = l & 15, lg = l >> 4;
    int wr = w >> 1, wc = w & 1;
    int row0 = blockIdx.y * 128, col0 = blockIdx.x * 128;

    f32x4 acc[4][4] = {};

    for (int k0 = 0; k0 < K; k0 += 32) {
#pragma unroll
        for (int i = 0; i < 2; i++) {
            int off = i * 4096 + t * 16;         // byte offset in 8KB tile
            int row = off >> 6;                  // 64B (=32 bf16) per row
            int cole = (off & 63) >> 1;          // element within row
            gl_lds16(A + (size_t)(row0 + row) * K + k0 + cole, (char*)As + off);
            gl_lds16(Bw + (size_t)(col0 + row) * K + k0 + cole, (char*)Bs + off);
        }
        asm volatile("s_waitcnt vmcnt(0)" ::: "memory");
        __syncthreads();

        short8 af[4], bf[4];
#pragma unroll
        for (int mi = 0; mi < 4; mi++)
            af[mi] = *(const short8*)(As + (wr * 64 + mi * 16 + lr) * 32 + lg * 8);
#pragma unroll
        for (int ni = 0; ni < 4; ni++)
            bf[ni] = *(const short8*)(Bs + (wc * 64 + ni * 16 + lr) * 32 + lg * 8);
#pragma unroll
        for (int mi = 0; mi < 4; mi++)
#pragma unroll
            for (int ni = 0; ni < 4; ni++)
                acc[mi][ni] = __builtin_amdgcn_mfma_f32_16x16x32_bf16(af[mi], bf[ni], acc[mi][ni], 0, 0, 0);
        __syncthreads();
    }

#pragma unroll
    for (int mi = 0; mi < 4; mi++) {
        int gr0 = row0 + wr * 64 + mi * 16 + lg * 4;
#pragma unroll
        for (int ni = 0; ni < 4; ni++) {
            int gc = col0 + wc * 64 + ni * 16 + lr;
            float bv = bias[gc];
#pragma unroll
            for (int r = 0; r < 4; r++) {
                float val = acc[mi][ni][r] + bv;
                int gr = gr0 + r;
                if (EPI == 0) {
                    int b = gr >> 11, tt = gr & 2047;
                    int sec = gc >> 11, c = gc & 2047;
                    int h = c >> 7, d = c & 127;
                    size_t idx = ((size_t)(b * H + h) * T + tt) * HD + d;
                    if (sec == 0) {
                        q_ws[idx] = f2bf(val);
                    } else if (sec == 1) {
                        outF[BTC + idx] = val;          // k f32 output
                        k_ws[idx] = f2bf(val);
                    } else {
                        outF[2 * BTC + idx] = val;      // v f32 output
                    }
                } else {
                    outF[(size_t)gr * Ndim + gc] = val;
                }
            }
        }
    }
}

// ---------- v [bh][T][HD] f32  ->  vT [bh][HD][T] bf16 ----------
__global__ void vtrans(const float* __restrict__ vin, short* __restrict__ vT) {
    __shared__ float tile[64 * 65];
    int blk = blockIdx.x;
    int bh = blk >> 6, rem = blk & 63;
    int t0 = (rem >> 1) * 64, d0 = (rem & 1) * 64;
    const float* src = vin + (size_t)bh * T * HD;
    short* dst = vT + (size_t)bh * HD * T;
    int t = threadIdx.x;
#pragma unroll
    for (int i = 0; i < 16; i++) {
        int idx = i * 256 + t;
        int r = idx >> 6, c = idx & 63;
        tile[r * 65 + c] = src[(size_t)(t0 + r) * HD + d0 + c];
    }
    __syncthreads();
#pragma unroll
    for (int i = 0; i < 16; i++) {
        int idx = i * 256 + t;
        int rd = idx >> 6, cc = idx & 63;
        dst[(size_t)(d0 + rd) * T + t0 + cc] = f2bf(tile[cc * 65 + rd]);
    }
}

// ---------- flash attention (non-causal), 4 waves x 16 q-rows, KV tiles of 64 ----------
__launch_bounds__(256)
__global__ void attn_fwd(const short* __restrict__ q_ws, const short* __restrict__ k_ws,
                         const short* __restrict__ vT_ws, short* __restrict__ ctx) {
    __shared__ __attribute__((aligned(16))) short K_lds[64 * 128];
    __shared__ __attribute__((aligned(16))) short VT_lds[128 * 64];
    __shared__ __attribute__((aligned(16))) short P_lds[4][16 * 64];

    int blk = blockIdx.x;
    int bh = blk >> 5;                 // 32 q-tiles per (b,h)
    int q0 = (blk & 31) * 64;
    int b = bh >> 4, h = bh & 15;
    int t = threadIdx.x, w = t >> 6, l = t & 63;
    int lr = l & 15, lg = l >> 4;

    // Q fragments in registers: row (w*16+lr), d = c*32 + lg*8 .. +8
    const short* Qp = q_ws + ((size_t)bh * T + q0 + w * 16 + lr) * HD;
    short8 qf[4];
#pragma unroll
    for (int c = 0; c < 4; c++) qf[c] = *(const short8*)(Qp + c * 32 + lg * 8);

    const short* Kp = k_ws + (size_t)bh * T * HD;
    const short* VTp = vT_ws + (size_t)bh * HD * T;

    const float SC = 0.12753123813884803f;  // (1/sqrt(128)) * log2(e)
    float m[4], lsum[4];
#pragma unroll
    for (int r = 0; r < 4; r++) { m[r] = -INFINITY; lsum[r] = 0.f; }
    f32x4 acc[8] = {};

    for (int kt = 0; kt < T / 64; kt++) {
        // stage K tile (contiguous 16KB) and VT tile (128 rows x 128B)
#pragma unroll
        for (int i = 0; i < 4; i++) {
            int off = i * 4096 + t * 16;
            gl_lds16((const char*)Kp + (size_t)kt * 16384 + off, (char*)K_lds + off);
            int row = off >> 7, cole = (off & 127) >> 1;
            gl_lds16(VTp + (size_t)row * T + kt * 64 + cole, (char*)VT_lds + off);
        }
        asm volatile("s_waitcnt vmcnt(0)" ::: "memory");
        __syncthreads();

        // S = Q K^T : A=Q, B=K (both d-contiguous)
        f32x4 sacc[4] = {};
#pragma unroll
        for (int kj = 0; kj < 4; kj++)
#pragma unroll
            for (int c = 0; c < 4; c++) {
                short8 kf = *(const short8*)(K_lds + (kj * 16 + lr) * 128 + c * 32 + lg * 8);
                sacc[kj] = __builtin_amdgcn_mfma_f32_16x16x32_bf16(qf[c], kf, sacc[kj], 0, 0, 0);
            }

        // online softmax (log2 domain); thread owns q rows lg*4+r, col lr
        float p[4][4];
#pragma unroll
        for (int r = 0; r < 4; r++) {
            float x0 = fmaxf(fmaxf(sacc[0][r], sacc[1][r]), fmaxf(sacc[2][r], sacc[3][r])) * SC;
#pragma unroll
            for (int d = 1; d < 16; d <<= 1) x0 = fmaxf(x0, __shfl_xor(x0, d));
            float mn = fmaxf(m[r], x0);
            float al = __builtin_exp2f(m[r] - mn);
            float s0 = 0.f;
#pragma unroll
            for (int kj = 0; kj < 4; kj++) {
                float pv = __builtin_exp2f(sacc[kj][r] * SC - mn);
                p[kj][r] = pv; s0 += pv;
            }
#pragma unroll
            for (int d = 1; d < 16; d <<= 1) s0 += __shfl_xor(s0, d);
            lsum[r] = lsum[r] * al + s0;
            m[r] = mn;
#pragma unroll
            for (int nj = 0; nj < 8; nj++) acc[nj][r] *= al;
        }

        // stage P (D-layout -> row-major [16 q][64 k] per wave)
#pragma unroll
        for (int kj = 0; kj < 4; kj++)
#pragma unroll
            for (int r = 0; r < 4; r++)
                P_lds[w][(lg * 4 + r) * 64 + kj * 16 + lr] = f2bf(p[kj][r]);
        asm volatile("s_waitcnt lgkmcnt(0)" ::: "memory");

        // O += P @ V  (A=P from LDS, B=V^T rows)
#pragma unroll
        for (int c2 = 0; c2 < 2; c2++) {
            short8 pf = *(const short8*)(&P_lds[w][lr * 64 + c2 * 32 + lg * 8]);
#pragma unroll
            for (int nj = 0; nj < 8; nj++) {
                short8 vf = *(const short8*)(VT_lds + (nj * 16 + lr) * 64 + c2 * 32 + lg * 8);
                acc[nj] = __builtin_amdgcn_mfma_f32_16x16x32_bf16(pf, vf, acc[nj], 0, 0, 0);
            }
        }
        __syncthreads();
    }

    // epilogue: ctx [B][T][C] bf16, col = h*128 + nj*16 + lr
#pragma unroll
    for (int r = 0; r < 4; r++) {
        float inv = 1.0f / lsum[r];
        int tq = q0 + w * 16 + lg * 4 + r;
        size_t base = ((size_t)b * T + tq) * C + h * HD;
#pragma unroll
        for (int nj = 0; nj < 8; nj++)
            ctx[base + nj * 16 + lr] = f2bf(acc[nj][r] * inv);
    }
}

extern "C" void kernel_launch(void* const* d_in, const int* in_sizes, int n_in,
                              void* d_out, int out_size, void* d_ws, size_t ws_size,
                              hipStream_t stream) {
    const float* x      = (const float*)d_in[0];
    const float* w_attn = (const float*)d_in[1];
    const float* b_attn = (const float*)d_in[2];
    const float* w_proj = (const float*)d_in[3];
    const float* b_proj = (const float*)d_in[4];
    float* out = (float*)d_out;

    // ws layout (58.7 MB):
    //   [0]          x_bf (16.78MB)  -> later wp_bf (8.39MB)
    //   [16777216]   wa_bf (25.17MB) -> later ctx  (16.78MB)
    //   [41943040]   vT   (16.78MB)
    char* ws = (char*)d_ws;
    short* x_bf  = (short*)ws;
    short* wp_bf = (short*)ws;                       // aliases x_bf (sequenced)
    short* wa_bf = (short*)(ws + 16777216);
    short* ctx   = (short*)(ws + 16777216);          // aliases wa_bf (sequenced)
    short* vT    = (short*)(ws + 41943040);

    // q/k bf16 scratch lives in the (not-yet-written) out section of d_out
    short* q_ws = (short*)d_out;                     // bytes [0, 16.78MB)
    short* k_ws = (short*)d_out + BTC;               // bytes [16.78MB, 33.55MB)

    cvt_bf16<<<4096, 256, 0, stream>>>(x, x_bf, (int)BTC);
    cvt_bf16<<<6144, 256, 0, stream>>>(w_attn, wa_bf, 3 * C * C);

    gemm_bt<0><<<dim3(48, 32), 256, 0, stream>>>(x_bf, wa_bf, b_attn, out, q_ws, k_ws,
                                                 M, 3 * C, C);

    vtrans<<<2048, 256, 0, stream>>>(out + 2 * BTC, vT);
    cvt_bf16<<<2048, 256, 0, stream>>>(w_proj, wp_bf, C * C);    // x_bf dead now

    attn_fwd<<<1024, 256, 0, stream>>>(q_ws, k_ws, vT, ctx);     // wa_bf dead now

    gemm_bt<1><<<dim3(16, 32), 256, 0, stream>>>(ctx, wp_bf, b_proj, out, nullptr, nullptr,
                                                 M, C, C);       // q_ws/k_ws dead now
}

// Round 2
// 348.255 us; speedup vs baseline: 1.4249x; 1.4249x over previous
//
#include <hip/hip_runtime.h>
#include <hip/hip_bf16.h>
#include <cstdint>
#include <cstddef>
#include <cmath>

typedef __attribute__((ext_vector_type(8))) short short8;
typedef __attribute__((ext_vector_type(4))) short bf16x4;
typedef __attribute__((ext_vector_type(4))) float f32x4;

static constexpr int BB = 2, T = 2048, C = 2048, H = 16, HD = 128;
static constexpr int M = BB * T;              // 4096
static constexpr size_t BTC = (size_t)BB * T * C;      // 8388608 (= B*H*T*HD)

__device__ __forceinline__ short f2bf(float f) {
    union { float f; uint32_t u; } v; v.f = f;
    uint32_t u = v.u;
    uint32_t r = (u + 0x7fffu + ((u >> 16) & 1u)) >> 16;
    return (short)r;
}

__device__ __forceinline__ short f2bf_fast(float f) {
    __hip_bfloat16 h = __float2bfloat16(f);   // compiler emits v_cvt_pk_bf16_f32 pairs
    return *reinterpret_cast<short*>(&h);
}

__device__ __forceinline__ void gl_lds16(const void* g, void* l) {
    __builtin_amdgcn_global_load_lds(
        (const __attribute__((address_space(1))) unsigned int*)g,
        (__attribute__((address_space(3))) unsigned int*)l, 16, 0, 0);
}

// ---------- f32 -> bf16 bulk convert (vectorized, G13) ----------
__global__ void cvt_bf16(const float* __restrict__ in, short* __restrict__ out, int n) {
    int i = (blockIdx.x * 256 + threadIdx.x) * 8;
    if (i >= n) return;
    float4 a = *(const float4*)(in + i);
    float4 b = *(const float4*)(in + i + 4);
    short8 o;
    o[0] = f2bf(a.x); o[1] = f2bf(a.y); o[2] = f2bf(a.z); o[3] = f2bf(a.w);
    o[4] = f2bf(b.x); o[5] = f2bf(b.y); o[6] = f2bf(b.z); o[7] = f2bf(b.w);
    *(short8*)(out + i) = o;
}

// ---------- 128x128 bf16 GEMM, C = A @ B^T + bias (m97 structure) ----------
template<int EPI>
__global__ void gemm_bt(const short* __restrict__ A, const short* __restrict__ Bw,
                        const float* __restrict__ bias,
                        float* __restrict__ outF,
                        short* __restrict__ q_ws, short* __restrict__ k_ws,
                        int Mdim, int Ndim, int K) {
    __shared__ __attribute__((aligned(16))) short As[128 * 32];
    __shared__ __attribute__((aligned(16))) short Bs[128 * 32];
    int t = threadIdx.x;
    int w = t >> 6, l = t & 63;
    int lr = l & 15, lg = l >> 4;
    int wr = w >> 1, wc = w & 1;
    int row0 = blockIdx.y * 128, col0 = blockIdx.x * 128;

    f32x4 acc[4][4] = {};

    for (int k0 = 0; k0 < K; k0 += 32) {
#pragma unroll
        for (int i = 0; i < 2; i++) {
            int off = i * 4096 + t * 16;         // byte offset in 8KB tile
            int row = off >> 6;                  // 64B (=32 bf16) per row
            int cole = (off & 63) >> 1;          // element within row
            gl_lds16(A + (size_t)(row0 + row) * K + k0 + cole, (char*)As + off);
            gl_lds16(Bw + (size_t)(col0 + row) * K + k0 + cole, (char*)Bs + off);
        }
        asm volatile("s_waitcnt vmcnt(0)" ::: "memory");
        __syncthreads();

        short8 af[4], bf[4];
#pragma unroll
        for (int mi = 0; mi < 4; mi++)
            af[mi] = *(const short8*)(As + (wr * 64 + mi * 16 + lr) * 32 + lg * 8);
#pragma unroll
        for (int ni = 0; ni < 4; ni++)
            bf[ni] = *(const short8*)(Bs + (wc * 64 + ni * 16 + lr) * 32 + lg * 8);
#pragma unroll
        for (int mi = 0; mi < 4; mi++)
#pragma unroll
            for (int ni = 0; ni < 4; ni++)
                acc[mi][ni] = __builtin_amdgcn_mfma_f32_16x16x32_bf16(af[mi], bf[ni], acc[mi][ni], 0, 0, 0);
        __syncthreads();
    }

#pragma unroll
    for (int mi = 0; mi < 4; mi++) {
        int gr0 = row0 + wr * 64 + mi * 16 + lg * 4;
#pragma unroll
        for (int ni = 0; ni < 4; ni++) {
            int gc = col0 + wc * 64 + ni * 16 + lr;
            float bv = bias[gc];
#pragma unroll
            for (int r = 0; r < 4; r++) {
                float val = acc[mi][ni][r] + bv;
                int gr = gr0 + r;
                if (EPI == 0) {
                    int b = gr >> 11, tt = gr & 2047;
                    int sec = gc >> 11, c = gc & 2047;
                    int h = c >> 7, d = c & 127;
                    size_t idx = ((size_t)(b * H + h) * T + tt) * HD + d;
                    if (sec == 0) {
                        q_ws[idx] = f2bf(val);
                    } else if (sec == 1) {
                        outF[BTC + idx] = val;          // k f32 output
                        k_ws[idx] = f2bf(val);
                    } else {
                        outF[2 * BTC + idx] = val;      // v f32 output
                    }
                } else {
                    outF[(size_t)gr * Ndim + gc] = val;
                }
            }
        }
    }
}

// ---------- v [bh][T][HD] f32  ->  vT [bh][HD][T] bf16 ----------
__global__ void vtrans(const float* __restrict__ vin, short* __restrict__ vT) {
    __shared__ float tile[64 * 65];
    int blk = blockIdx.x;
    int bh = blk >> 6, rem = blk & 63;
    int t0 = (rem >> 1) * 64, d0 = (rem & 1) * 64;
    const float* src = vin + (size_t)bh * T * HD;
    short* dst = vT + (size_t)bh * HD * T;
    int t = threadIdx.x;
#pragma unroll
    for (int i = 0; i < 16; i++) {
        int idx = i * 256 + t;
        int r = idx >> 6, c = idx & 63;
        tile[r * 65 + c] = src[(size_t)(t0 + r) * HD + d0 + c];
    }
    __syncthreads();
#pragma unroll
    for (int i = 0; i < 16; i++) {
        int idx = i * 256 + t;
        int rd = idx >> 6, cc = idx & 63;
        dst[(size_t)(d0 + rd) * T + t0 + cc] = f2bf(tile[cc * 65 + rd]);
    }
}

// ---------- flash attention (non-causal), swapped-QK^T + XOR-swizzled LDS ----------
// 4 waves x 16 q-rows, KV tiles of 64. S^T = mfma(K, Q) puts a full q-row slice
// in each lane (q = lane&15): softmax is lane-local + 2 shfl over lg; P staged
// as 4 x ds_write_b64. All LDS tiles XOR-swizzled (byte ^= (row&7)<<4).
__launch_bounds__(256)
__global__ void attn_fwd(const short* __restrict__ q_ws, const short* __restrict__ k_ws,
                         const short* __restrict__ vT_ws, short* __restrict__ ctx) {
    __shared__ __attribute__((aligned(16))) char K_lds[64 * 256];    // [64 k][128 d] bf16
    __shared__ __attribute__((aligned(16))) char VT_lds[128 * 128];  // [128 d][64 k] bf16
    __shared__ __attribute__((aligned(16))) char P_lds[4][16 * 128]; // per-wave [16 q][64 k]

    int blk = blockIdx.x;
    int bh = blk >> 5;                 // 32 q-tiles per (b,h)
    int q0 = (blk & 31) * 64;
    int b = bh >> 4, h = bh & 15;
    int t = threadIdx.x, w = t >> 6, l = t & 63;
    int lr = l & 15, lg = l >> 4;
    int sw = (lr & 7) << 4;            // read-side XOR swizzle (row&7 == lr&7 everywhere)

    // Q fragments in registers: row (w*16+lr), d = c*32 + lg*8 .. +8
    const short* Qp = q_ws + ((size_t)bh * T + q0 + w * 16 + lr) * HD;
    short8 qf[4];
#pragma unroll
    for (int c = 0; c < 4; c++) qf[c] = *(const short8*)(Qp + c * 32 + lg * 8);

    const char* Kp = (const char*)(k_ws + (size_t)bh * T * HD);
    const short* VTp = vT_ws + (size_t)bh * HD * T;
    char* Pc = P_lds[w];

    const float SC = 0.12753123813884803f;  // (1/sqrt(128)) * log2(e)
    float m = -INFINITY, lsum = 0.f;        // per-lane, for q-row lr (dup over lg)
    f32x4 acc[8] = {};

    for (int kt = 0; kt < T / 64; kt++) {
        // stage K tile (64x128 bf16, 256B rows) and VT tile (128x64 bf16, 128B rows)
        // linear LDS dest + inverse-swizzled global source (rule #21)
#pragma unroll
        for (int i = 0; i < 4; i++) {
            int off = i * 4096 + t * 16;
            int swzK = off ^ (((off >> 8) & 7) << 4);
            gl_lds16(Kp + (size_t)kt * 16384 + swzK, K_lds + off);
            int swzV = off ^ (((off >> 7) & 7) << 4);
            int row = swzV >> 7, cole = (swzV & 127) >> 1;
            gl_lds16(VTp + (size_t)row * T + kt * 64 + cole, VT_lds + off);
        }
        asm volatile("s_waitcnt vmcnt(0)" ::: "memory");
        __syncthreads();

        // S^T = K Q^T : lane holds S[q=lr][k = kt*64 + kj*16 + lg*4 + r]
        f32x4 sacc[4] = {};
#pragma unroll
        for (int kj = 0; kj < 4; kj++) {
            int rowb = (kj * 16 + lr) * 256;
#pragma unroll
            for (int c = 0; c < 4; c++) {
                short8 kf = *(const short8*)(K_lds + ((rowb + c * 64 + lg * 16) ^ sw));
                sacc[kj] = __builtin_amdgcn_mfma_f32_16x16x32_bf16(kf, qf[c], sacc[kj], 0, 0, 0);
            }
        }

        // online softmax, lane-local per q-row (log2 domain)
        float xm = sacc[0][0];
#pragma unroll
        for (int kj = 0; kj < 4; kj++)
#pragma unroll
            for (int r = 0; r < 4; r++) xm = fmaxf(xm, sacc[kj][r]);
        xm *= SC;
        xm = fmaxf(xm, __shfl_xor(xm, 16));
        xm = fmaxf(xm, __shfl_xor(xm, 32));

        if (!__all(xm <= m + 8.0f)) {          // T13 defer-max, THR=8 (log2 units)
            float mn = fmaxf(m, xm);
            float al = __builtin_exp2f(m - mn);
            m = mn;
            lsum *= al;
            float ar[4];
#pragma unroll
            for (int r = 0; r < 4; r++) ar[r] = __shfl(al, lg * 4 + r);
#pragma unroll
            for (int nj = 0; nj < 8; nj++)
#pragma unroll
                for (int r = 0; r < 4; r++) acc[nj][r] *= ar[r];
        }

        float s0 = 0.f;
#pragma unroll
        for (int kj = 0; kj < 4; kj++) {
            bf16x4 pk;
#pragma unroll
            for (int r = 0; r < 4; r++) {
                float pv = __builtin_exp2f(sacc[kj][r] * SC - m);
                s0 += pv;
                pk[r] = f2bf_fast(pv);
            }
            *(bf16x4*)(Pc + ((lr * 128 + kj * 32 + lg * 8) ^ sw)) = pk;
        }
        s0 += __shfl_xor(s0, 16);
        s0 += __shfl_xor(s0, 32);
        lsum += s0;

        asm volatile("s_waitcnt lgkmcnt(0)" ::: "memory");

        // O += P @ V  (A = P rows, B = V^T rows; both swizzle-read)
#pragma unroll
        for (int c2 = 0; c2 < 2; c2++) {
            short8 pf = *(const short8*)(Pc + ((lr * 128 + c2 * 64 + lg * 16) ^ sw));
#pragma unroll
            for (int nj = 0; nj < 8; nj++) {
                short8 vf = *(const short8*)(VT_lds + (((nj * 16 + lr) * 128 + c2 * 64 + lg * 16) ^ sw));
                acc[nj] = __builtin_amdgcn_mfma_f32_16x16x32_bf16(pf, vf, acc[nj], 0, 0, 0);
            }
        }
        __syncthreads();
    }

    // epilogue: ctx [B][T][C] bf16; acc[nj][r] = O[q = w*16 + lg*4 + r][d = nj*16 + lr]
#pragma unroll
    for (int r = 0; r < 4; r++) {
        float rs = __shfl(lsum, lg * 4 + r);
        float inv = 1.0f / rs;
        int tq = q0 + w * 16 + lg * 4 + r;
        size_t base = ((size_t)b * T + tq) * C + h * HD;
#pragma unroll
        for (int nj = 0; nj < 8; nj++)
            ctx[base + nj * 16 + lr] = f2bf_fast(acc[nj][r] * inv);
    }
}

extern "C" void kernel_launch(void* const* d_in, const int* in_sizes, int n_in,
                              void* d_out, int out_size, void* d_ws, size_t ws_size,
                              hipStream_t stream) {
    const float* x      = (const float*)d_in[0];
    const float* w_attn = (const float*)d_in[1];
    const float* b_attn = (const float*)d_in[2];
    const float* w_proj = (const float*)d_in[3];
    const float* b_proj = (const float*)d_in[4];
    float* out = (float*)d_out;

    // ws layout (58.7 MB):
    //   [0]          x_bf (16.78MB)  -> later wp_bf (8.39MB)
    //   [16777216]   wa_bf (25.17MB) -> later ctx  (16.78MB)
    //   [41943040]   vT   (16.78MB)
    char* ws = (char*)d_ws;
    short* x_bf  = (short*)ws;
    short* wp_bf = (short*)ws;                       // aliases x_bf (sequenced)
    short* wa_bf = (short*)(ws + 16777216);
    short* ctx   = (short*)(ws + 16777216);          // aliases wa_bf (sequenced)
    short* vT    = (short*)(ws + 41943040);

    // q/k bf16 scratch lives in the (not-yet-written) out section of d_out
    short* q_ws = (short*)d_out;                     // bytes [0, 16.78MB)
    short* k_ws = (short*)d_out + BTC;               // bytes [16.78MB, 33.55MB)

    cvt_bf16<<<4096, 256, 0, stream>>>(x, x_bf, (int)BTC);
    cvt_bf16<<<6144, 256, 0, stream>>>(w_attn, wa_bf, 3 * C * C);

    gemm_bt<0><<<dim3(48, 32), 256, 0, stream>>>(x_bf, wa_bf, b_attn, out, q_ws, k_ws,
                                                 M, 3 * C, C);

    vtrans<<<2048, 256, 0, stream>>>(out + 2 * BTC, vT);
    cvt_bf16<<<2048, 256, 0, stream>>>(w_proj, wp_bf, C * C);    // x_bf dead now

    attn_fwd<<<1024, 256, 0, stream>>>(q_ws, k_ws, vT, ctx);     // wa_bf dead now

    gemm_bt<1><<<dim3(16, 32), 256, 0, stream>>>(ctx, wp_bf, b_proj, out, nullptr, nullptr,
                                                 M, C, C);       // q_ws/k_ws dead now
}

// Round 3
// 327.578 us; speedup vs baseline: 1.5148x; 1.0631x over previous
//
#include <hip/hip_runtime.h>
#include <hip/hip_bf16.h>
#include <cstdint>
#include <cstddef>
#include <cmath>

typedef __attribute__((ext_vector_type(8))) short short8;
typedef __attribute__((ext_vector_type(4))) short bf16x4;
typedef __attribute__((ext_vector_type(4))) float f32x4;

static constexpr int BB = 2, T = 2048, C = 2048, H = 16, HD = 128;
static constexpr int M = BB * T;              // 4096
static constexpr size_t BTC = (size_t)BB * T * C;      // 8388608 (= B*H*T*HD)

__device__ __forceinline__ short f2bf(float f) {
    union { float f; uint32_t u; } v; v.f = f;
    uint32_t u = v.u;
    uint32_t r = (u + 0x7fffu + ((u >> 16) & 1u)) >> 16;
    return (short)r;
}

__device__ __forceinline__ short f2bf_fast(float f) {
    __hip_bfloat16 h = __float2bfloat16(f);
    return *reinterpret_cast<short*>(&h);
}

__device__ __forceinline__ void gl_lds16(const void* g, void* l) {
    __builtin_amdgcn_global_load_lds(
        (const __attribute__((address_space(1))) unsigned int*)g,
        (__attribute__((address_space(3))) unsigned int*)l, 16, 0, 0);
}

// ---------- f32 -> bf16 bulk convert ----------
__global__ void cvt_bf16(const float* __restrict__ in, short* __restrict__ out, int n) {
    int i = (blockIdx.x * 256 + threadIdx.x) * 8;
    if (i >= n) return;
    float4 a = *(const float4*)(in + i);
    float4 b = *(const float4*)(in + i + 4);
    short8 o;
    o[0] = f2bf(a.x); o[1] = f2bf(a.y); o[2] = f2bf(a.z); o[3] = f2bf(a.w);
    o[4] = f2bf(b.x); o[5] = f2bf(b.y); o[6] = f2bf(b.z); o[7] = f2bf(b.w);
    *(short8*)(out + i) = o;
}

// ---------- QKV GEMM: 256x192 tile, BK=64, 8 waves, dbuf LDS, counted vmcnt ----------
// A [4096][2048] bf16, Bw [6144][2048] bf16 (row-major in K; C = A B^T + bias).
// Schedule per K-tile t: 4 phases {ds_read frags, setprio(1), 12 MFMA, setprio(0)}
//   -> s_barrier (all reads of buf[t&1] done)
//   -> issue 7 global_load_lds staging tile t+2 into buf[t&1]
//   -> s_waitcnt vmcnt(7)  (tile t+1 landed; t+2's 7 loads stay in flight)
//   -> s_barrier.
// LDS XOR-swizzle byte^=((row&7)<<4); write side via inverse-swizzled global src.
__launch_bounds__(512, 2)
__global__ void gemm_qkv256(const short* __restrict__ A, const short* __restrict__ Bw,
                            const float* __restrict__ bias, float* __restrict__ outF,
                            short* __restrict__ q_ws, short* __restrict__ k_ws) {
    extern __shared__ char lds[];
    constexpr int K = 2048, NKT = K / 64;
    constexpr int BUFSZ = 57344;          // 32KB A + 24KB B per buffer

    // XCD-bijective swizzle: 512 blocks = 8 XCDs x 64
    int bid = blockIdx.x;
    int swz = (bid & 7) * 64 + (bid >> 3);
    int by = swz >> 5, bx = swz & 31;     // by: 16 M-tiles, bx: 32 N-tiles
    int row0 = by * 256, col0 = bx * 192;

    int t = threadIdx.x, w = t >> 6, l = t & 63;
    int lr = l & 15, lg = l >> 4;
    int wr = w >> 2, wc = w & 3;          // 2 x 4 wave grid; wave owns 128 x 48

    // staging bases: 7 chunks of 8KB (A: c=0..3, B: c=4..6); per-thread 16B slot
    const char* Ab = (const char*)A;
    const char* Bb = (const char*)Bw;
    const char* srcb[7];
    int dstoff[7];
#pragma unroll
    for (int c = 0; c < 7; c++) {
        bool isA = c < 4;
        int coff = (isA ? c : c - 4) * 8192 + t * 16;
        int row = coff >> 7;
        int colb = (coff & 127) ^ ((row & 7) << 4);   // inverse-swizzled source col
        srcb[c] = isA ? Ab + (size_t)(row0 + row) * (K * 2) + colb
                      : Bb + (size_t)(col0 + row) * (K * 2) + colb;
        dstoff[c] = (isA ? 0 : 32768) + coff;
    }

    f32x4 acc[8][3] = {};

    // prologue: stage tiles 0 and 1
#pragma unroll
    for (int c = 0; c < 7; c++) gl_lds16(srcb[c], lds + dstoff[c]);
#pragma unroll
    for (int c = 0; c < 7; c++) gl_lds16(srcb[c] + 128, lds + BUFSZ + dstoff[c]);
    asm volatile("s_waitcnt vmcnt(7)" ::: "memory");
    __builtin_amdgcn_s_barrier();

    for (int kt = 0; kt < NKT; kt++) {
        const char* Abase = lds + (kt & 1) * BUFSZ;
        const char* Bbase = Abase + 32768;

        short8 bfr[3][2];
#pragma unroll
        for (int p = 0; p < 4; p++) {
            short8 af[2][2];
#pragma unroll
            for (int mi2 = 0; mi2 < 2; mi2++) {
                int row = wr * 128 + p * 32 + mi2 * 16 + lr;
#pragma unroll
                for (int ks = 0; ks < 2; ks++)
                    af[mi2][ks] = *(const short8*)(Abase + row * 128 +
                                  ((ks * 64 + lg * 16) ^ ((row & 7) << 4)));
            }
            if (p == 0) {
#pragma unroll
                for (int ni = 0; ni < 3; ni++) {
                    int row = wc * 48 + ni * 16 + lr;
#pragma unroll
                    for (int ks = 0; ks < 2; ks++)
                        bfr[ni][ks] = *(const short8*)(Bbase + row * 128 +
                                      ((ks * 64 + lg * 16) ^ ((row & 7) << 4)));
                }
            }
            __builtin_amdgcn_s_setprio(1);
#pragma unroll
            for (int ks = 0; ks < 2; ks++)
#pragma unroll
                for (int mi2 = 0; mi2 < 2; mi2++)
#pragma unroll
                    for (int ni = 0; ni < 3; ni++)
                        acc[p * 2 + mi2][ni] = __builtin_amdgcn_mfma_f32_16x16x32_bf16(
                            af[mi2][ks], bfr[ni][ks], acc[p * 2 + mi2][ni], 0, 0, 0);
            __builtin_amdgcn_s_setprio(0);
        }

        __builtin_amdgcn_s_barrier();      // all waves done reading buf[kt&1]
        if (kt + 2 < NKT) {
            int koff = (kt + 2) * 128;
            char* dbase = lds + (kt & 1) * BUFSZ;
#pragma unroll
            for (int c = 0; c < 7; c++) gl_lds16(srcb[c] + koff, dbase + dstoff[c]);
            asm volatile("s_waitcnt vmcnt(7)" ::: "memory");   // tile kt+1 landed
        } else {
            asm volatile("s_waitcnt vmcnt(0)" ::: "memory");   // tail drain
        }
        __builtin_amdgcn_s_barrier();      // tile kt+1 visible to all waves
    }

    // epilogue: scatter q (bf16), k (f32 + bf16), v (f32)
#pragma unroll
    for (int mi = 0; mi < 8; mi++) {
        int gr0 = row0 + wr * 128 + mi * 16 + lg * 4;
#pragma unroll
        for (int ni = 0; ni < 3; ni++) {
            int gc = col0 + wc * 48 + ni * 16 + lr;
            float bv = bias[gc];
            int sec = gc >> 11, cc = gc & 2047;
            int h = cc >> 7, d = cc & 127;
#pragma unroll
            for (int r = 0; r < 4; r++) {
                float val = acc[mi][ni][r] + bv;
                int gr = gr0 + r;
                int b = gr >> 11, tt = gr & 2047;
                size_t idx = ((size_t)(b * H + h) * T + tt) * HD + d;
                if (sec == 0) {
                    q_ws[idx] = f2bf(val);
                } else if (sec == 1) {
                    outF[BTC + idx] = val;
                    k_ws[idx] = f2bf(val);
                } else {
                    outF[2 * BTC + idx] = val;
                }
            }
        }
    }
}

// ---------- 128x128 bf16 GEMM, C = A @ B^T + bias (m97 structure) — proj only ----------
__global__ void gemm_bt(const short* __restrict__ A, const short* __restrict__ Bw,
                        const float* __restrict__ bias, float* __restrict__ outF,
                        int Ndim, int K) {
    __shared__ __attribute__((aligned(16))) short As[128 * 32];
    __shared__ __attribute__((aligned(16))) short Bs[128 * 32];
    int t = threadIdx.x;
    int w = t >> 6, l = t & 63;
    int lr = l & 15, lg = l >> 4;
    int wr = w >> 1, wc = w & 1;
    int row0 = blockIdx.y * 128, col0 = blockIdx.x * 128;

    f32x4 acc[4][4] = {};

    for (int k0 = 0; k0 < K; k0 += 32) {
#pragma unroll
        for (int i = 0; i < 2; i++) {
            int off = i * 4096 + t * 16;
            int row = off >> 6;
            int cole = (off & 63) >> 1;
            gl_lds16(A + (size_t)(row0 + row) * K + k0 + cole, (char*)As + off);
            gl_lds16(Bw + (size_t)(col0 + row) * K + k0 + cole, (char*)Bs + off);
        }
        asm volatile("s_waitcnt vmcnt(0)" ::: "memory");
        __syncthreads();

        short8 af[4], bf[4];
#pragma unroll
        for (int mi = 0; mi < 4; mi++)
            af[mi] = *(const short8*)(As + (wr * 64 + mi * 16 + lr) * 32 + lg * 8);
#pragma unroll
        for (int ni = 0; ni < 4; ni++)
            bf[ni] = *(const short8*)(Bs + (wc * 64 + ni * 16 + lr) * 32 + lg * 8);
#pragma unroll
        for (int mi = 0; mi < 4; mi++)
#pragma unroll
            for (int ni = 0; ni < 4; ni++)
                acc[mi][ni] = __builtin_amdgcn_mfma_f32_16x16x32_bf16(af[mi], bf[ni], acc[mi][ni], 0, 0, 0);
        __syncthreads();
    }

#pragma unroll
    for (int mi = 0; mi < 4; mi++) {
        int gr0 = row0 + wr * 64 + mi * 16 + lg * 4;
#pragma unroll
        for (int ni = 0; ni < 4; ni++) {
            int gc = col0 + wc * 64 + ni * 16 + lr;
            float bv = bias[gc];
#pragma unroll
            for (int r = 0; r < 4; r++)
                outF[(size_t)(gr0 + r) * Ndim + gc] = acc[mi][ni][r] + bv;
        }
    }
}

// ---------- v [bh][T][HD] f32  ->  vT [bh][HD][T] bf16 ----------
__global__ void vtrans(const float* __restrict__ vin, short* __restrict__ vT) {
    __shared__ float tile[64 * 65];
    int blk = blockIdx.x;
    int bh = blk >> 6, rem = blk & 63;
    int t0 = (rem >> 1) * 64, d0 = (rem & 1) * 64;
    const float* src = vin + (size_t)bh * T * HD;
    short* dst = vT + (size_t)bh * HD * T;
    int t = threadIdx.x;
#pragma unroll
    for (int i = 0; i < 16; i++) {
        int idx = i * 256 + t;
        int r = idx >> 6, c = idx & 63;
        tile[r * 65 + c] = src[(size_t)(t0 + r) * HD + d0 + c];
    }
    __syncthreads();
#pragma unroll
    for (int i = 0; i < 16; i++) {
        int idx = i * 256 + t;
        int rd = idx >> 6, cc = idx & 63;
        dst[(size_t)(d0 + rd) * T + t0 + cc] = f2bf(tile[cc * 65 + rd]);
    }
}

// ---------- flash attention (non-causal), swapped-QK^T + XOR-swizzled LDS ----------
__launch_bounds__(256)
__global__ void attn_fwd(const short* __restrict__ q_ws, const short* __restrict__ k_ws,
                         const short* __restrict__ vT_ws, short* __restrict__ ctx) {
    __shared__ __attribute__((aligned(16))) char K_lds[64 * 256];    // [64 k][128 d] bf16
    __shared__ __attribute__((aligned(16))) char VT_lds[128 * 128];  // [128 d][64 k] bf16
    __shared__ __attribute__((aligned(16))) char P_lds[4][16 * 128]; // per-wave [16 q][64 k]

    int blk = blockIdx.x;
    int bh = blk >> 5;
    int q0 = (blk & 31) * 64;
    int b = bh >> 4, h = bh & 15;
    int t = threadIdx.x, w = t >> 6, l = t & 63;
    int lr = l & 15, lg = l >> 4;
    int sw = (lr & 7) << 4;

    const short* Qp = q_ws + ((size_t)bh * T + q0 + w * 16 + lr) * HD;
    short8 qf[4];
#pragma unroll
    for (int c = 0; c < 4; c++) qf[c] = *(const short8*)(Qp + c * 32 + lg * 8);

    const char* Kp = (const char*)(k_ws + (size_t)bh * T * HD);
    const short* VTp = vT_ws + (size_t)bh * HD * T;
    char* Pc = P_lds[w];

    const float SC = 0.12753123813884803f;  // (1/sqrt(128)) * log2(e)
    float m = -INFINITY, lsum = 0.f;
    f32x4 acc[8] = {};

    for (int kt = 0; kt < T / 64; kt++) {
#pragma unroll
        for (int i = 0; i < 4; i++) {
            int off = i * 4096 + t * 16;
            int swzK = off ^ (((off >> 8) & 7) << 4);
            gl_lds16(Kp + (size_t)kt * 16384 + swzK, K_lds + off);
            int swzV = off ^ (((off >> 7) & 7) << 4);
            int row = swzV >> 7, cole = (swzV & 127) >> 1;
            gl_lds16(VTp + (size_t)row * T + kt * 64 + cole, VT_lds + off);
        }
        asm volatile("s_waitcnt vmcnt(0)" ::: "memory");
        __syncthreads();

        f32x4 sacc[4] = {};
#pragma unroll
        for (int kj = 0; kj < 4; kj++) {
            int rowb = (kj * 16 + lr) * 256;
#pragma unroll
            for (int c = 0; c < 4; c++) {
                short8 kf = *(const short8*)(K_lds + ((rowb + c * 64 + lg * 16) ^ sw));
                sacc[kj] = __builtin_amdgcn_mfma_f32_16x16x32_bf16(kf, qf[c], sacc[kj], 0, 0, 0);
            }
        }

        float xm = sacc[0][0];
#pragma unroll
        for (int kj = 0; kj < 4; kj++)
#pragma unroll
            for (int r = 0; r < 4; r++) xm = fmaxf(xm, sacc[kj][r]);
        xm *= SC;
        xm = fmaxf(xm, __shfl_xor(xm, 16));
        xm = fmaxf(xm, __shfl_xor(xm, 32));

        if (!__all(xm <= m + 8.0f)) {
            float mn = fmaxf(m, xm);
            float al = __builtin_exp2f(m - mn);
            m = mn;
            lsum *= al;
            float ar[4];
#pragma unroll
            for (int r = 0; r < 4; r++) ar[r] = __shfl(al, lg * 4 + r);
#pragma unroll
            for (int nj = 0; nj < 8; nj++)
#pragma unroll
                for (int r = 0; r < 4; r++) acc[nj][r] *= ar[r];
        }

        float s0 = 0.f;
#pragma unroll
        for (int kj = 0; kj < 4; kj++) {
            bf16x4 pk;
#pragma unroll
            for (int r = 0; r < 4; r++) {
                float pv = __builtin_exp2f(sacc[kj][r] * SC - m);
                s0 += pv;
                pk[r] = f2bf_fast(pv);
            }
            *(bf16x4*)(Pc + ((lr * 128 + kj * 32 + lg * 8) ^ sw)) = pk;
        }
        s0 += __shfl_xor(s0, 16);
        s0 += __shfl_xor(s0, 32);
        lsum += s0;

        asm volatile("s_waitcnt lgkmcnt(0)" ::: "memory");

#pragma unroll
        for (int c2 = 0; c2 < 2; c2++) {
            short8 pf = *(const short8*)(Pc + ((lr * 128 + c2 * 64 + lg * 16) ^ sw));
#pragma unroll
            for (int nj = 0; nj < 8; nj++) {
                short8 vf = *(const short8*)(VT_lds + (((nj * 16 + lr) * 128 + c2 * 64 + lg * 16) ^ sw));
                acc[nj] = __builtin_amdgcn_mfma_f32_16x16x32_bf16(pf, vf, acc[nj], 0, 0, 0);
            }
        }
        __syncthreads();
    }

#pragma unroll
    for (int r = 0; r < 4; r++) {
        float rs = __shfl(lsum, lg * 4 + r);
        float inv = 1.0f / rs;
        int tq = q0 + w * 16 + lg * 4 + r;
        size_t base = ((size_t)b * T + tq) * C + h * HD;
#pragma unroll
        for (int nj = 0; nj < 8; nj++)
            ctx[base + nj * 16 + lr] = f2bf_fast(acc[nj][r] * inv);
    }
}

extern "C" void kernel_launch(void* const* d_in, const int* in_sizes, int n_in,
                              void* d_out, int out_size, void* d_ws, size_t ws_size,
                              hipStream_t stream) {
    const float* x      = (const float*)d_in[0];
    const float* w_attn = (const float*)d_in[1];
    const float* b_attn = (const float*)d_in[2];
    const float* w_proj = (const float*)d_in[3];
    const float* b_proj = (const float*)d_in[4];
    float* out = (float*)d_out;

    char* ws = (char*)d_ws;
    short* x_bf  = (short*)ws;
    short* wp_bf = (short*)ws;                       // aliases x_bf (sequenced)
    short* wa_bf = (short*)(ws + 16777216);
    short* ctx   = (short*)(ws + 16777216);          // aliases wa_bf (sequenced)
    short* vT    = (short*)(ws + 41943040);

    short* q_ws = (short*)d_out;                     // out section reused as scratch
    short* k_ws = (short*)d_out + BTC;

    hipFuncSetAttribute((const void*)gemm_qkv256,
                        hipFuncAttributeMaxDynamicSharedMemorySize, 114688);

    cvt_bf16<<<4096, 256, 0, stream>>>(x, x_bf, (int)BTC);
    cvt_bf16<<<6144, 256, 0, stream>>>(w_attn, wa_bf, 3 * C * C);

    gemm_qkv256<<<512, 512, 114688, stream>>>(x_bf, wa_bf, b_attn, out, q_ws, k_ws);

    vtrans<<<2048, 256, 0, stream>>>(out + 2 * BTC, vT);
    cvt_bf16<<<2048, 256, 0, stream>>>(w_proj, wp_bf, C * C);    // x_bf dead now

    attn_fwd<<<1024, 256, 0, stream>>>(q_ws, k_ws, vT, ctx);     // wa_bf dead now

    gemm_bt<<<dim3(16, 32), 256, 0, stream>>>(ctx, wp_bf, b_proj, out, C, C);
}

// Round 4
// 303.237 us; speedup vs baseline: 1.6364x; 1.0803x over previous
//
#include <hip/hip_runtime.h>
#include <hip/hip_bf16.h>
#include <cstdint>
#include <cstddef>
#include <cmath>

typedef __attribute__((ext_vector_type(8))) short short8;
typedef __attribute__((ext_vector_type(4))) short bf16x4;
typedef __attribute__((ext_vector_type(4))) float f32x4;

static constexpr int BB = 2, T = 2048, C = 2048, H = 16, HD = 128;
static constexpr int M = BB * T;              // 4096
static constexpr size_t BTC = (size_t)BB * T * C;      // 8388608 (= B*H*T*HD)

__device__ __forceinline__ short f2bf(float f) {
    union { float f; uint32_t u; } v; v.f = f;
    uint32_t u = v.u;
    uint32_t r = (u + 0x7fffu + ((u >> 16) & 1u)) >> 16;
    return (short)r;
}

__device__ __forceinline__ short f2bf_fast(float f) {
    __hip_bfloat16 h = __float2bfloat16(f);
    return *reinterpret_cast<short*>(&h);
}

__device__ __forceinline__ void gl_lds16(const void* g, void* l) {
    __builtin_amdgcn_global_load_lds(
        (const __attribute__((address_space(1))) unsigned int*)g,
        (__attribute__((address_space(3))) unsigned int*)l, 16, 0, 0);
}

// ---------- f32 -> bf16 bulk convert ----------
__global__ void cvt_bf16(const float* __restrict__ in, short* __restrict__ out, int n) {
    int i = (blockIdx.x * 256 + threadIdx.x) * 8;
    if (i >= n) return;
    float4 a = *(const float4*)(in + i);
    float4 b = *(const float4*)(in + i + 4);
    short8 o;
    o[0] = f2bf(a.x); o[1] = f2bf(a.y); o[2] = f2bf(a.z); o[3] = f2bf(a.w);
    o[4] = f2bf(b.x); o[5] = f2bf(b.y); o[6] = f2bf(b.z); o[7] = f2bf(b.w);
    *(short8*)(out + i) = o;
}

// ---------- QKV GEMM: 256x192 tile, BK=64, 8 waves, dbuf LDS, counted vmcnt ----------
__launch_bounds__(512, 2)
__global__ void gemm_qkv256(const short* __restrict__ A, const short* __restrict__ Bw,
                            const float* __restrict__ bias, float* __restrict__ outF,
                            short* __restrict__ q_ws, short* __restrict__ k_ws) {
    extern __shared__ char lds[];
    constexpr int K = 2048, NKT = K / 64;
    constexpr int BUFSZ = 57344;          // 32KB A + 24KB B per buffer

    int bid = blockIdx.x;
    int swz = (bid & 7) * 64 + (bid >> 3);
    int by = swz >> 5, bx = swz & 31;
    int row0 = by * 256, col0 = bx * 192;

    int t = threadIdx.x, w = t >> 6, l = t & 63;
    int lr = l & 15, lg = l >> 4;
    int wr = w >> 2, wc = w & 3;

    const char* Ab = (const char*)A;
    const char* Bb = (const char*)Bw;
    const char* srcb[7];
    int dstoff[7];
#pragma unroll
    for (int c = 0; c < 7; c++) {
        bool isA = c < 4;
        int coff = (isA ? c : c - 4) * 8192 + t * 16;
        int row = coff >> 7;
        int colb = (coff & 127) ^ ((row & 7) << 4);
        srcb[c] = isA ? Ab + (size_t)(row0 + row) * (K * 2) + colb
                      : Bb + (size_t)(col0 + row) * (K * 2) + colb;
        dstoff[c] = (isA ? 0 : 32768) + coff;
    }

    f32x4 acc[8][3] = {};

#pragma unroll
    for (int c = 0; c < 7; c++) gl_lds16(srcb[c], lds + dstoff[c]);
#pragma unroll
    for (int c = 0; c < 7; c++) gl_lds16(srcb[c] + 128, lds + BUFSZ + dstoff[c]);
    asm volatile("s_waitcnt vmcnt(7)" ::: "memory");
    __builtin_amdgcn_s_barrier();

    for (int kt = 0; kt < NKT; kt++) {
        const char* Abase = lds + (kt & 1) * BUFSZ;
        const char* Bbase = Abase + 32768;

        short8 bfr[3][2];
#pragma unroll
        for (int p = 0; p < 4; p++) {
            short8 af[2][2];
#pragma unroll
            for (int mi2 = 0; mi2 < 2; mi2++) {
                int row = wr * 128 + p * 32 + mi2 * 16 + lr;
#pragma unroll
                for (int ks = 0; ks < 2; ks++)
                    af[mi2][ks] = *(const short8*)(Abase + row * 128 +
                                  ((ks * 64 + lg * 16) ^ ((row & 7) << 4)));
            }
            if (p == 0) {
#pragma unroll
                for (int ni = 0; ni < 3; ni++) {
                    int row = wc * 48 + ni * 16 + lr;
#pragma unroll
                    for (int ks = 0; ks < 2; ks++)
                        bfr[ni][ks] = *(const short8*)(Bbase + row * 128 +
                                      ((ks * 64 + lg * 16) ^ ((row & 7) << 4)));
                }
            }
            __builtin_amdgcn_s_setprio(1);
#pragma unroll
            for (int ks = 0; ks < 2; ks++)
#pragma unroll
                for (int mi2 = 0; mi2 < 2; mi2++)
#pragma unroll
                    for (int ni = 0; ni < 3; ni++)
                        acc[p * 2 + mi2][ni] = __builtin_amdgcn_mfma_f32_16x16x32_bf16(
                            af[mi2][ks], bfr[ni][ks], acc[p * 2 + mi2][ni], 0, 0, 0);
            __builtin_amdgcn_s_setprio(0);
        }

        __builtin_amdgcn_s_barrier();
        if (kt + 2 < NKT) {
            int koff = (kt + 2) * 128;
            char* dbase = lds + (kt & 1) * BUFSZ;
#pragma unroll
            for (int c = 0; c < 7; c++) gl_lds16(srcb[c] + koff, dbase + dstoff[c]);
            asm volatile("s_waitcnt vmcnt(7)" ::: "memory");
        } else {
            asm volatile("s_waitcnt vmcnt(0)" ::: "memory");
        }
        __builtin_amdgcn_s_barrier();
    }

#pragma unroll
    for (int mi = 0; mi < 8; mi++) {
        int gr0 = row0 + wr * 128 + mi * 16 + lg * 4;
#pragma unroll
        for (int ni = 0; ni < 3; ni++) {
            int gc = col0 + wc * 48 + ni * 16 + lr;
            float bv = bias[gc];
            int sec = gc >> 11, cc = gc & 2047;
            int h = cc >> 7, d = cc & 127;
#pragma unroll
            for (int r = 0; r < 4; r++) {
                float val = acc[mi][ni][r] + bv;
                int gr = gr0 + r;
                int b = gr >> 11, tt = gr & 2047;
                size_t idx = ((size_t)(b * H + h) * T + tt) * HD + d;
                if (sec == 0) {
                    q_ws[idx] = f2bf(val);
                } else if (sec == 1) {
                    outF[BTC + idx] = val;
                    k_ws[idx] = f2bf(val);
                } else {
                    outF[2 * BTC + idx] = val;
                }
            }
        }
    }
}

// ---------- proj GEMM: 128x128 bf16, C = A @ B^T + bias (m97 structure) ----------
__global__ void gemm_proj(const short* __restrict__ A, const short* __restrict__ Bw,
                          const float* __restrict__ bias, float* __restrict__ outF,
                          int Ndim, int K) {
    __shared__ __attribute__((aligned(16))) short As[128 * 32];
    __shared__ __attribute__((aligned(16))) short Bs[128 * 32];
    int t = threadIdx.x;
    int w = t >> 6, l = t & 63;
    int lr = l & 15, lg = l >> 4;
    int wr = w >> 1, wc = w & 1;
    int row0 = blockIdx.y * 128, col0 = blockIdx.x * 128;

    f32x4 acc[4][4] = {};

    for (int k0 = 0; k0 < K; k0 += 32) {
#pragma unroll
        for (int i = 0; i < 2; i++) {
            int off = i * 4096 + t * 16;
            int row = off >> 6;
            int cole = (off & 63) >> 1;
            gl_lds16(A + (size_t)(row0 + row) * K + k0 + cole, (char*)As + off);
            gl_lds16(Bw + (size_t)(col0 + row) * K + k0 + cole, (char*)Bs + off);
        }
        asm volatile("s_waitcnt vmcnt(0)" ::: "memory");
        __syncthreads();

        short8 af[4], bf[4];
#pragma unroll
        for (int mi = 0; mi < 4; mi++)
            af[mi] = *(const short8*)(As + (wr * 64 + mi * 16 + lr) * 32 + lg * 8);
#pragma unroll
        for (int ni = 0; ni < 4; ni++)
            bf[ni] = *(const short8*)(Bs + (wc * 64 + ni * 16 + lr) * 32 + lg * 8);
#pragma unroll
        for (int mi = 0; mi < 4; mi++)
#pragma unroll
            for (int ni = 0; ni < 4; ni++)
                acc[mi][ni] = __builtin_amdgcn_mfma_f32_16x16x32_bf16(af[mi], bf[ni], acc[mi][ni], 0, 0, 0);
        __syncthreads();
    }

#pragma unroll
    for (int mi = 0; mi < 4; mi++) {
        int gr0 = row0 + wr * 64 + mi * 16 + lg * 4;
#pragma unroll
        for (int ni = 0; ni < 4; ni++) {
            int gc = col0 + wc * 64 + ni * 16 + lr;
            float bv = bias[gc];
#pragma unroll
            for (int r = 0; r < 4; r++)
                outF[(size_t)(gr0 + r) * Ndim + gc] = acc[mi][ni][r] + bv;
        }
    }
}

// ---------- v [bh][T][HD] f32  ->  vT [bh][HD][T] bf16 ----------
__global__ void vtrans(const float* __restrict__ vin, short* __restrict__ vT) {
    __shared__ float tile[64 * 65];
    int blk = blockIdx.x;
    int bh = blk >> 6, rem = blk & 63;
    int t0 = (rem >> 1) * 64, d0 = (rem & 1) * 64;
    const float* src = vin + (size_t)bh * T * HD;
    short* dst = vT + (size_t)bh * HD * T;
    int t = threadIdx.x;
#pragma unroll
    for (int i = 0; i < 16; i++) {
        int idx = i * 256 + t;
        int r = idx >> 6, c = idx & 63;
        tile[r * 65 + c] = src[(size_t)(t0 + r) * HD + d0 + c];
    }
    __syncthreads();
#pragma unroll
    for (int i = 0; i < 16; i++) {
        int idx = i * 256 + t;
        int rd = idx >> 6, cc = idx & 63;
        dst[(size_t)(d0 + rd) * T + t0 + cc] = f2bf(tile[cc * 65 + rd]);
    }
}

// ---------- flash attention: 4 waves x 32 q-rows, KVBLK=64, K/V double-buffered ----------
// Swapped QK^T (lane owns q-row lr), XOR-swizzled LDS, T3-minimal stage-ahead.
__launch_bounds__(256, 2)
__global__ void attn_fwd(const short* __restrict__ q_ws, const short* __restrict__ k_ws,
                         const short* __restrict__ vT_ws, short* __restrict__ ctx) {
    __shared__ __attribute__((aligned(16))) char K_lds[2][64 * 256];   // dbuf [64 k][128 d]
    __shared__ __attribute__((aligned(16))) char VT_lds[2][128 * 128]; // dbuf [128 d][64 k]
    __shared__ __attribute__((aligned(16))) char P_lds[4][16 * 128];   // per-wave [16 q][64 k]

    int bid = blockIdx.x;
    int blk = (bid & 7) * 64 + (bid >> 3);     // XCD-bijective (512 = 8*64)
    int bh = blk >> 4;                          // 16 q-tiles of 128 per (b,h)
    int q0 = (blk & 15) * 128;
    int b = bh >> 4, h = bh & 15;
    int t = threadIdx.x, w = t >> 6, l = t & 63;
    int lr = l & 15, lg = l >> 4;
    int sw = (lr & 7) << 4;

    // Q fragments: wave covers q0 + w*32 .. +31, two 16-row subtiles
    short8 qf[2][4];
#pragma unroll
    for (int qt = 0; qt < 2; qt++) {
        const short* Qp = q_ws + ((size_t)bh * T + q0 + w * 32 + qt * 16 + lr) * HD;
#pragma unroll
        for (int c = 0; c < 4; c++) qf[qt][c] = *(const short8*)(Qp + c * 32 + lg * 8);
    }

    const char* Kp = (const char*)(k_ws + (size_t)bh * T * HD);
    const short* VTp = vT_ws + (size_t)bh * HD * T;
    char* Pc = P_lds[w];

    const float SC = 0.12753123813884803f;  // (1/sqrt(128)) * log2(e)
    float m[2] = {-INFINITY, -INFINITY}, lsum[2] = {0.f, 0.f};
    f32x4 acc[2][8] = {};

    auto STAGE = [&](int kt, int bsel) {
#pragma unroll
        for (int i = 0; i < 4; i++) {
            int off = i * 4096 + t * 16;
            int swzK = off ^ (((off >> 8) & 7) << 4);
            gl_lds16(Kp + (size_t)kt * 16384 + swzK, K_lds[bsel] + off);
            int swzV = off ^ (((off >> 7) & 7) << 4);
            int row = swzV >> 7, cole = (swzV & 127) >> 1;
            gl_lds16(VTp + (size_t)row * T + kt * 64 + cole, VT_lds[bsel] + off);
        }
    };

    STAGE(0, 0);
    asm volatile("s_waitcnt vmcnt(0)" ::: "memory");
    __syncthreads();

    for (int kt = 0; kt < T / 64; kt++) {
        int cur = kt & 1;
        if (kt + 1 < T / 64) STAGE(kt + 1, cur ^ 1);   // hide HBM under compute
        const char* Kc = K_lds[cur];
        const char* Vc = VT_lds[cur];

        // S^T = K Q^T for both q-subtiles; kf read once, used twice
        f32x4 sacc[2][4] = {};
#pragma unroll
        for (int kj = 0; kj < 4; kj++) {
            int rowb = (kj * 16 + lr) * 256;
#pragma unroll
            for (int c = 0; c < 4; c++) {
                short8 kf = *(const short8*)(Kc + ((rowb + c * 64 + lg * 16) ^ sw));
                sacc[0][kj] = __builtin_amdgcn_mfma_f32_16x16x32_bf16(kf, qf[0][c], sacc[0][kj], 0, 0, 0);
                sacc[1][kj] = __builtin_amdgcn_mfma_f32_16x16x32_bf16(kf, qf[1][c], sacc[1][kj], 0, 0, 0);
            }
        }

#pragma unroll
        for (int qt = 0; qt < 2; qt++) {
            // tree max over 16 lane-local values
            float t0 = fmaxf(fmaxf(sacc[qt][0][0], sacc[qt][0][1]), fmaxf(sacc[qt][0][2], sacc[qt][0][3]));
            float t1 = fmaxf(fmaxf(sacc[qt][1][0], sacc[qt][1][1]), fmaxf(sacc[qt][1][2], sacc[qt][1][3]));
            float t2 = fmaxf(fmaxf(sacc[qt][2][0], sacc[qt][2][1]), fmaxf(sacc[qt][2][2], sacc[qt][2][3]));
            float t3 = fmaxf(fmaxf(sacc[qt][3][0], sacc[qt][3][1]), fmaxf(sacc[qt][3][2], sacc[qt][3][3]));
            float xm = fmaxf(fmaxf(t0, t1), fmaxf(t2, t3)) * SC;
            xm = fmaxf(xm, __shfl_xor(xm, 16));
            xm = fmaxf(xm, __shfl_xor(xm, 32));

            if (!__all(xm <= m[qt] + 8.0f)) {          // T13 defer-max
                float mn = fmaxf(m[qt], xm);
                float al = __builtin_exp2f(m[qt] - mn);
                m[qt] = mn;
                lsum[qt] *= al;
                float ar[4];
#pragma unroll
                for (int r = 0; r < 4; r++) ar[r] = __shfl(al, lg * 4 + r);
#pragma unroll
                for (int nj = 0; nj < 8; nj++)
#pragma unroll
                    for (int r = 0; r < 4; r++) acc[qt][nj][r] *= ar[r];
            }

            float s0 = 0.f;
#pragma unroll
            for (int kj = 0; kj < 4; kj++) {
                bf16x4 pk;
#pragma unroll
                for (int r = 0; r < 4; r++) {
                    float pv = __builtin_exp2f(__builtin_fmaf(sacc[qt][kj][r], SC, -m[qt]));
                    s0 += pv;
                    pk[r] = f2bf_fast(pv);
                }
                *(bf16x4*)(Pc + ((lr * 128 + kj * 32 + lg * 8) ^ sw)) = pk;
            }
            s0 += __shfl_xor(s0, 16);
            s0 += __shfl_xor(s0, 32);
            lsum[qt] += s0;

            asm volatile("s_waitcnt lgkmcnt(0)" ::: "memory");

#pragma unroll
            for (int c2 = 0; c2 < 2; c2++) {
                short8 pf = *(const short8*)(Pc + ((lr * 128 + c2 * 64 + lg * 16) ^ sw));
#pragma unroll
                for (int nj = 0; nj < 8; nj++) {
                    short8 vf = *(const short8*)(Vc + (((nj * 16 + lr) * 128 + c2 * 64 + lg * 16) ^ sw));
                    acc[qt][nj] = __builtin_amdgcn_mfma_f32_16x16x32_bf16(pf, vf, acc[qt][nj], 0, 0, 0);
                }
            }
        }

        asm volatile("s_waitcnt vmcnt(0)" ::: "memory");   // stage(kt+1) landed
        __syncthreads();
    }

    // epilogue: ctx [B][T][C] bf16
#pragma unroll
    for (int qt = 0; qt < 2; qt++)
#pragma unroll
        for (int r = 0; r < 4; r++) {
            float rs = __shfl(lsum[qt], lg * 4 + r);
            float inv = 1.0f / rs;
            int tq = q0 + w * 32 + qt * 16 + lg * 4 + r;
            size_t base = ((size_t)b * T + tq) * C + h * HD;
#pragma unroll
            for (int nj = 0; nj < 8; nj++)
                ctx[base + nj * 16 + lr] = f2bf_fast(acc[qt][nj][r] * inv);
        }
}

extern "C" void kernel_launch(void* const* d_in, const int* in_sizes, int n_in,
                              void* d_out, int out_size, void* d_ws, size_t ws_size,
                              hipStream_t stream) {
    const float* x      = (const float*)d_in[0];
    const float* w_attn = (const float*)d_in[1];
    const float* b_attn = (const float*)d_in[2];
    const float* w_proj = (const float*)d_in[3];
    const float* b_proj = (const float*)d_in[4];
    float* out = (float*)d_out;

    char* ws = (char*)d_ws;
    short* x_bf  = (short*)ws;
    short* wp_bf = (short*)ws;                       // aliases x_bf (sequenced)
    short* wa_bf = (short*)(ws + 16777216);
    short* ctx   = (short*)(ws + 16777216);          // aliases wa_bf (sequenced)
    short* vT    = (short*)(ws + 41943040);

    short* q_ws = (short*)d_out;                     // out section reused as scratch
    short* k_ws = (short*)d_out + BTC;

    hipFuncSetAttribute((const void*)gemm_qkv256,
                        hipFuncAttributeMaxDynamicSharedMemorySize, 114688);

    cvt_bf16<<<4096, 256, 0, stream>>>(x, x_bf, (int)BTC);
    cvt_bf16<<<6144, 256, 0, stream>>>(w_attn, wa_bf, 3 * C * C);

    gemm_qkv256<<<512, 512, 114688, stream>>>(x_bf, wa_bf, b_attn, out, q_ws, k_ws);

    vtrans<<<2048, 256, 0, stream>>>(out + 2 * BTC, vT);
    cvt_bf16<<<2048, 256, 0, stream>>>(w_proj, wp_bf, C * C);    // x_bf dead now

    attn_fwd<<<512, 256, 0, stream>>>(q_ws, k_ws, vT, ctx);      // wa_bf dead now

    gemm_proj<<<dim3(16, 32), 256, 0, stream>>>(ctx, wp_bf, b_proj, out, C, C);
}

// Round 5
// 293.690 us; speedup vs baseline: 1.6896x; 1.0325x over previous
//
#include <hip/hip_runtime.h>
#include <hip/hip_bf16.h>
#include <cstdint>
#include <cstddef>
#include <cmath>

typedef __attribute__((ext_vector_type(8))) short short8;
typedef __attribute__((ext_vector_type(4))) short bf16x4;
typedef __attribute__((ext_vector_type(4))) float f32x4;

static constexpr int BB = 2, T = 2048, C = 2048, H = 16, HD = 128;
static constexpr int M = BB * T;              // 4096
static constexpr size_t BTC = (size_t)BB * T * C;      // 8388608 (= B*H*T*HD)

__device__ __forceinline__ short f2bf(float f) {
    union { float f; uint32_t u; } v; v.f = f;
    uint32_t u = v.u;
    uint32_t r = (u + 0x7fffu + ((u >> 16) & 1u)) >> 16;
    return (short)r;
}

__device__ __forceinline__ short f2bf_fast(float f) {
    __hip_bfloat16 h = __float2bfloat16(f);
    return *reinterpret_cast<short*>(&h);
}

__device__ __forceinline__ void gl_lds16(const void* g, void* l) {
    __builtin_amdgcn_global_load_lds(
        (const __attribute__((address_space(1))) unsigned int*)g,
        (__attribute__((address_space(3))) unsigned int*)l, 16, 0, 0);
}

// ---------- f32 -> bf16 bulk convert ----------
__global__ void cvt_bf16(const float* __restrict__ in, short* __restrict__ out, int n) {
    int i = (blockIdx.x * 256 + threadIdx.x) * 8;
    if (i >= n) return;
    float4 a = *(const float4*)(in + i);
    float4 b = *(const float4*)(in + i + 4);
    short8 o;
    o[0] = f2bf(a.x); o[1] = f2bf(a.y); o[2] = f2bf(a.z); o[3] = f2bf(a.w);
    o[4] = f2bf(b.x); o[5] = f2bf(b.y); o[6] = f2bf(b.z); o[7] = f2bf(b.w);
    *(short8*)(out + i) = o;
}

// ---------- unified 8-phase-style GEMM: BM=256, BN=NI*64, BK=64, 8 waves ----------
// C = A @ B^T + bias. A [Mrows][2048] bf16, Bw [Ncols][2048] bf16.
// Per K-tile: 4 phases {ds_read quadrant -> s_barrier -> setprio+MFMA -> sched_barrier
// -> s_barrier -> issue freed chunks of tile kt+2}. Stage issues spread (B after p0,
// A0/A2 after p1, A1/A3 after p3; each region's readers passed the post-MFMA barrier
// => WAR-safe). Single counted vmcnt(NCH) per tile, never 0 in the main loop (T4).
// LDS XOR-swizzle byte^=((row&7)<<4), write-side via inverse-swizzled global source.
template<int NI, int EPI, int NBX>
__launch_bounds__(512, 2)
__global__ void gemm8p(const short* __restrict__ A, const short* __restrict__ Bw,
                       const float* __restrict__ bias, float* __restrict__ outF,
                       short* __restrict__ q_ws, short* __restrict__ k_ws, int Ndim) {
    extern __shared__ char lds[];
    constexpr int K = 2048, NKT = K / 64;
    constexpr int NCH = 4 + NI;                 // 8KB chunks per tile (A:4, B:NI)
    constexpr int BUFSZ = 32768 + NI * 8192;

    int bid = blockIdx.x;
    int nwg = gridDim.x;
    int swz = (bid & 7) * (nwg >> 3) + (bid >> 3);   // XCD-bijective (nwg % 8 == 0)
    int by = swz / NBX, bx = swz % NBX;
    int row0 = by * 256, col0 = bx * (NI * 64);

    int t = threadIdx.x, w = t >> 6, l = t & 63;
    int lr = l & 15, lg = l >> 4;
    int wr = w >> 2, wc = w & 3;                // 2 x 4 waves; wave owns 128 x NI*16

    const char* srcb[NCH];
    int dstoff[NCH];
#pragma unroll
    for (int c = 0; c < NCH; c++) {
        bool isA = c < 4;
        int coff = (isA ? c : c - 4) * 8192 + t * 16;
        int row = coff >> 7;                    // 128B (=64 bf16) per row
        int colb = (coff & 127) ^ ((row & 7) << 4);
        srcb[c] = isA ? (const char*)A + (size_t)(row0 + row) * (K * 2) + colb
                      : (const char*)Bw + (size_t)(col0 + row) * (K * 2) + colb;
        dstoff[c] = (isA ? 0 : 32768) + coff;
    }

    f32x4 acc[8][NI] = {};

    // prologue: stage tiles 0 and 1
#pragma unroll
    for (int c = 0; c < NCH; c++) gl_lds16(srcb[c], lds + dstoff[c]);
#pragma unroll
    for (int c = 0; c < NCH; c++) gl_lds16(srcb[c] + 128, lds + BUFSZ + dstoff[c]);
    asm volatile("s_waitcnt vmcnt(%0)" :: "n"(NCH) : "memory");
    __builtin_amdgcn_s_barrier();

    for (int kt = 0; kt < NKT; kt++) {
        char* base = lds + (kt & 1) * BUFSZ;
        const char* Bbase = base + 32768;
        int koff = (kt + 2) * 128;
        bool pf = (kt + 2 < NKT);

        short8 bfr[NI][2];
#pragma unroll
        for (int p = 0; p < 4; p++) {
            short8 af[2][2];
#pragma unroll
            for (int mi2 = 0; mi2 < 2; mi2++) {
                int row = wr * 128 + p * 32 + mi2 * 16 + lr;
#pragma unroll
                for (int ks = 0; ks < 2; ks++)
                    af[mi2][ks] = *(const short8*)(base + row * 128 +
                                  ((ks * 64 + lg * 16) ^ ((row & 7) << 4)));
            }
            if (p == 0) {
#pragma unroll
                for (int ni = 0; ni < NI; ni++) {
                    int row = wc * (NI * 16) + ni * 16 + lr;
#pragma unroll
                    for (int ks = 0; ks < 2; ks++)
                        bfr[ni][ks] = *(const short8*)(Bbase + row * 128 +
                                      ((ks * 64 + lg * 16) ^ ((row & 7) << 4)));
                }
            }
            __builtin_amdgcn_s_barrier();            // split ds_read | MFMA (role diversity)
            __builtin_amdgcn_s_setprio(1);
#pragma unroll
            for (int ks = 0; ks < 2; ks++)
#pragma unroll
                for (int mi2 = 0; mi2 < 2; mi2++)
#pragma unroll
                    for (int ni = 0; ni < NI; ni++)
                        acc[p * 2 + mi2][ni] = __builtin_amdgcn_mfma_f32_16x16x32_bf16(
                            af[mi2][ks], bfr[ni][ks], acc[p * 2 + mi2][ni], 0, 0, 0);
            __builtin_amdgcn_s_setprio(0);
            __builtin_amdgcn_sched_barrier(0);       // pin MFMA before barrier (rule #18/#19)
            __builtin_amdgcn_s_barrier();            // region of phase p fully consumed

            // stage-issue freed chunks of tile kt+2 into buf[cur]
            if (p == 0 && pf) {
                asm volatile("" ::: "memory");
#pragma unroll
                for (int c = 4; c < NCH; c++) gl_lds16(srcb[c] + koff, base + dstoff[c]);
            }
            if (p == 1 && pf) {
                asm volatile("" ::: "memory");
                gl_lds16(srcb[0] + koff, base + dstoff[0]);
                gl_lds16(srcb[2] + koff, base + dstoff[2]);
            }
            if (p == 3) {
                if (pf) {
                    asm volatile("" ::: "memory");
                    gl_lds16(srcb[1] + koff, base + dstoff[1]);
                    gl_lds16(srcb[3] + koff, base + dstoff[3]);
                    asm volatile("s_waitcnt vmcnt(%0)" :: "n"(NCH) : "memory"); // kt+1 landed
                } else {
                    asm volatile("s_waitcnt vmcnt(0)" ::: "memory");            // tail drain
                }
                __builtin_amdgcn_s_barrier();
            }
        }
    }

    // epilogue
#pragma unroll
    for (int mi = 0; mi < 8; mi++) {
        int gr0 = row0 + wr * 128 + mi * 16 + lg * 4;
#pragma unroll
        for (int ni = 0; ni < NI; ni++) {
            int gc = col0 + wc * (NI * 16) + ni * 16 + lr;
            float bv = bias[gc];
            if (EPI == 0) {
                int sec = gc >> 11, cc = gc & 2047;
                int h = cc >> 7, d = cc & 127;
#pragma unroll
                for (int r = 0; r < 4; r++) {
                    float val = acc[mi][ni][r] + bv;
                    int gr = gr0 + r;
                    int b = gr >> 11, tt = gr & 2047;
                    size_t idx = ((size_t)(b * H + h) * T + tt) * HD + d;
                    if (sec == 0) {
                        q_ws[idx] = f2bf(val);
                    } else if (sec == 1) {
                        outF[BTC + idx] = val;
                        k_ws[idx] = f2bf(val);
                    } else {
                        outF[2 * BTC + idx] = val;
                    }
                }
            } else {
#pragma unroll
                for (int r = 0; r < 4; r++)
                    outF[(size_t)(gr0 + r) * Ndim + gc] = acc[mi][ni][r] + bv;
            }
        }
    }
}

// ---------- v [bh][T][HD] f32  ->  vT [bh][HD][T] bf16 ----------
__global__ void vtrans(const float* __restrict__ vin, short* __restrict__ vT) {
    __shared__ float tile[64 * 65];
    int blk = blockIdx.x;
    int bh = blk >> 6, rem = blk & 63;
    int t0 = (rem >> 1) * 64, d0 = (rem & 1) * 64;
    const float* src = vin + (size_t)bh * T * HD;
    short* dst = vT + (size_t)bh * HD * T;
    int t = threadIdx.x;
#pragma unroll
    for (int i = 0; i < 16; i++) {
        int idx = i * 256 + t;
        int r = idx >> 6, c = idx & 63;
        tile[r * 65 + c] = src[(size_t)(t0 + r) * HD + d0 + c];
    }
    __syncthreads();
#pragma unroll
    for (int i = 0; i < 16; i++) {
        int idx = i * 256 + t;
        int rd = idx >> 6, cc = idx & 63;
        dst[(size_t)(d0 + rd) * T + t0 + cc] = f2bf(tile[cc * 65 + rd]);
    }
}

// ---------- flash attention: 4 waves x 32 q-rows, KVBLK=64, K/V double-buffered ----------
__launch_bounds__(256, 2)
__global__ void attn_fwd(const short* __restrict__ q_ws, const short* __restrict__ k_ws,
                         const short* __restrict__ vT_ws, short* __restrict__ ctx) {
    __shared__ __attribute__((aligned(16))) char K_lds[2][64 * 256];   // dbuf [64 k][128 d]
    __shared__ __attribute__((aligned(16))) char VT_lds[2][128 * 128]; // dbuf [128 d][64 k]
    __shared__ __attribute__((aligned(16))) char P_lds[4][16 * 128];   // per-wave [16 q][64 k]

    int bid = blockIdx.x;
    int blk = (bid & 7) * 64 + (bid >> 3);     // XCD-bijective (512 = 8*64)
    int bh = blk >> 4;                          // 16 q-tiles of 128 per (b,h)
    int q0 = (blk & 15) * 128;
    int b = bh >> 4, h = bh & 15;
    int t = threadIdx.x, w = t >> 6, l = t & 63;
    int lr = l & 15, lg = l >> 4;
    int sw = (lr & 7) << 4;

    short8 qf[2][4];
#pragma unroll
    for (int qt = 0; qt < 2; qt++) {
        const short* Qp = q_ws + ((size_t)bh * T + q0 + w * 32 + qt * 16 + lr) * HD;
#pragma unroll
        for (int c = 0; c < 4; c++) qf[qt][c] = *(const short8*)(Qp + c * 32 + lg * 8);
    }

    const char* Kp = (const char*)(k_ws + (size_t)bh * T * HD);
    const short* VTp = vT_ws + (size_t)bh * HD * T;
    char* Pc = P_lds[w];

    const float SC = 0.12753123813884803f;  // (1/sqrt(128)) * log2(e)
    float m[2] = {-INFINITY, -INFINITY}, lsum[2] = {0.f, 0.f};
    f32x4 acc[2][8] = {};

    auto STAGE = [&](int kt, int bsel) {
#pragma unroll
        for (int i = 0; i < 4; i++) {
            int off = i * 4096 + t * 16;
            int swzK = off ^ (((off >> 8) & 7) << 4);
            gl_lds16(Kp + (size_t)kt * 16384 + swzK, K_lds[bsel] + off);
            int swzV = off ^ (((off >> 7) & 7) << 4);
            int row = swzV >> 7, cole = (swzV & 127) >> 1;
            gl_lds16(VTp + (size_t)row * T + kt * 64 + cole, VT_lds[bsel] + off);
        }
    };

    STAGE(0, 0);
    asm volatile("s_waitcnt vmcnt(0)" ::: "memory");
    __syncthreads();

    for (int kt = 0; kt < T / 64; kt++) {
        int cur = kt & 1;
        if (kt + 1 < T / 64) STAGE(kt + 1, cur ^ 1);
        const char* Kc = K_lds[cur];
        const char* Vc = VT_lds[cur];

        f32x4 sacc[2][4] = {};
#pragma unroll
        for (int kj = 0; kj < 4; kj++) {
            int rowb = (kj * 16 + lr) * 256;
#pragma unroll
            for (int c = 0; c < 4; c++) {
                short8 kf = *(const short8*)(Kc + ((rowb + c * 64 + lg * 16) ^ sw));
                sacc[0][kj] = __builtin_amdgcn_mfma_f32_16x16x32_bf16(kf, qf[0][c], sacc[0][kj], 0, 0, 0);
                sacc[1][kj] = __builtin_amdgcn_mfma_f32_16x16x32_bf16(kf, qf[1][c], sacc[1][kj], 0, 0, 0);
            }
        }

#pragma unroll
        for (int qt = 0; qt < 2; qt++) {
            float t0 = fmaxf(fmaxf(sacc[qt][0][0], sacc[qt][0][1]), fmaxf(sacc[qt][0][2], sacc[qt][0][3]));
            float t1 = fmaxf(fmaxf(sacc[qt][1][0], sacc[qt][1][1]), fmaxf(sacc[qt][1][2], sacc[qt][1][3]));
            float t2 = fmaxf(fmaxf(sacc[qt][2][0], sacc[qt][2][1]), fmaxf(sacc[qt][2][2], sacc[qt][2][3]));
            float t3 = fmaxf(fmaxf(sacc[qt][3][0], sacc[qt][3][1]), fmaxf(sacc[qt][3][2], sacc[qt][3][3]));
            float xm = fmaxf(fmaxf(t0, t1), fmaxf(t2, t3)) * SC;
            xm = fmaxf(xm, __shfl_xor(xm, 16));
            xm = fmaxf(xm, __shfl_xor(xm, 32));

            if (!__all(xm <= m[qt] + 8.0f)) {          // T13 defer-max
                float mn = fmaxf(m[qt], xm);
                float al = __builtin_exp2f(m[qt] - mn);
                m[qt] = mn;
                lsum[qt] *= al;
                float ar[4];
#pragma unroll
                for (int r = 0; r < 4; r++) ar[r] = __shfl(al, lg * 4 + r);
#pragma unroll
                for (int nj = 0; nj < 8; nj++)
#pragma unroll
                    for (int r = 0; r < 4; r++) acc[qt][nj][r] *= ar[r];
            }

            float s0 = 0.f;
#pragma unroll
            for (int kj = 0; kj < 4; kj++) {
                bf16x4 pk;
#pragma unroll
                for (int r = 0; r < 4; r++) {
                    float pv = __builtin_exp2f(__builtin_fmaf(sacc[qt][kj][r], SC, -m[qt]));
                    s0 += pv;
                    pk[r] = f2bf_fast(pv);
                }
                *(bf16x4*)(Pc + ((lr * 128 + kj * 32 + lg * 8) ^ sw)) = pk;
            }
            s0 += __shfl_xor(s0, 16);
            s0 += __shfl_xor(s0, 32);
            lsum[qt] += s0;

            asm volatile("s_waitcnt lgkmcnt(0)" ::: "memory");

#pragma unroll
            for (int c2 = 0; c2 < 2; c2++) {
                short8 pf = *(const short8*)(Pc + ((lr * 128 + c2 * 64 + lg * 16) ^ sw));
#pragma unroll
                for (int nj = 0; nj < 8; nj++) {
                    short8 vf = *(const short8*)(Vc + (((nj * 16 + lr) * 128 + c2 * 64 + lg * 16) ^ sw));
                    acc[qt][nj] = __builtin_amdgcn_mfma_f32_16x16x32_bf16(pf, vf, acc[qt][nj], 0, 0, 0);
                }
            }
        }

        asm volatile("s_waitcnt vmcnt(0)" ::: "memory");
        __syncthreads();
    }

#pragma unroll
    for (int qt = 0; qt < 2; qt++)
#pragma unroll
        for (int r = 0; r < 4; r++) {
            float rs = __shfl(lsum[qt], lg * 4 + r);
            float inv = 1.0f / rs;
            int tq = q0 + w * 32 + qt * 16 + lg * 4 + r;
            size_t base = ((size_t)b * T + tq) * C + h * HD;
#pragma unroll
            for (int nj = 0; nj < 8; nj++)
                ctx[base + nj * 16 + lr] = f2bf_fast(acc[qt][nj][r] * inv);
        }
}

extern "C" void kernel_launch(void* const* d_in, const int* in_sizes, int n_in,
                              void* d_out, int out_size, void* d_ws, size_t ws_size,
                              hipStream_t stream) {
    const float* x      = (const float*)d_in[0];
    const float* w_attn = (const float*)d_in[1];
    const float* b_attn = (const float*)d_in[2];
    const float* w_proj = (const float*)d_in[3];
    const float* b_proj = (const float*)d_in[4];
    float* out = (float*)d_out;

    char* ws = (char*)d_ws;
    short* x_bf  = (short*)ws;
    short* wp_bf = (short*)ws;                       // aliases x_bf (sequenced)
    short* wa_bf = (short*)(ws + 16777216);
    short* ctx   = (short*)(ws + 16777216);          // aliases wa_bf (sequenced)
    short* vT    = (short*)(ws + 41943040);

    short* q_ws = (short*)d_out;                     // out section reused as scratch
    short* k_ws = (short*)d_out + BTC;

    hipFuncSetAttribute((const void*)gemm8p<3, 0, 32>,
                        hipFuncAttributeMaxDynamicSharedMemorySize, 114688);
    hipFuncSetAttribute((const void*)gemm8p<2, 1, 16>,
                        hipFuncAttributeMaxDynamicSharedMemorySize, 98304);

    cvt_bf16<<<4096, 256, 0, stream>>>(x, x_bf, (int)BTC);
    cvt_bf16<<<6144, 256, 0, stream>>>(w_attn, wa_bf, 3 * C * C);

    // QKV: M=4096 (16 row-tiles), N=6144 (32 col-tiles of 192) -> 512 blocks = 2 rounds
    gemm8p<3, 0, 32><<<512, 512, 114688, stream>>>(x_bf, wa_bf, b_attn, out, q_ws, k_ws, 6144);

    vtrans<<<2048, 256, 0, stream>>>(out + 2 * BTC, vT);
    cvt_bf16<<<2048, 256, 0, stream>>>(w_proj, wp_bf, C * C);    // x_bf dead now

    attn_fwd<<<512, 256, 0, stream>>>(q_ws, k_ws, vT, ctx);      // wa_bf dead now

    // proj: M=4096 (16), N=2048 (16 col-tiles of 128) -> 256 blocks = exactly 1 round
    gemm8p<2, 1, 16><<<256, 512, 98304, stream>>>(ctx, wp_bf, b_proj, out, nullptr, nullptr, 2048);
}